// Round 6
// baseline (143.775 us; speedup 1.0000x reference)
//
#include <hip/hip_runtime.h>

// B=32, G=512
// out layout: [rel_pos (B,G,G,3) | rel_ori (B,G,G,3,3)] flat f32
//
// Direct-store kernel, no LDS / no barriers / no fences:
// lane L of a wave owns flat output float j0*9 + L of an ori row
// (63 lanes = 7 j  x 9 components, both STATIC per lane), and
// j0*3 + L of a pos row (63 = 21 j x 3 comps). Every wave store
// instruction is 252 contiguous bytes; each lane computes exactly
// the dword it stores. Persistent grid: 8192 waves x 2 rows each.

#define G_ 512
#define NB 32

__global__ __launch_bounds__(256, 8) void relposori_kernel(
    const float* __restrict__ center,   // (B,G,6)
    const float* __restrict__ lrf,      // (B,G,3,3)
    float* __restrict__ out_pos,        // (B,G,G,3)
    float* __restrict__ out_ori)        // (B,G,G,3,3)
{
    int tid  = threadIdx.x;
    int lane = tid & 63;
    int w    = tid >> 6;
    int wave_id = __builtin_amdgcn_readfirstlane(blockIdx.x * 4 + w); // 0..8191

    // static per-lane decompositions (lanes 0..62 active)
    int jj9 = lane / 9, c9 = lane % 9;     // ori: j-offset, component
    int m   = c9 / 3,   n  = c9 % 3;       // c = m*3+n
    int jj3 = lane / 3, c3 = lane % 3;     // pos: j-offset, component

    // each wave owns rows [2*wave_id, 2*wave_id+1] of 16384 (b,i) rows
    for (int rr = 0; rr < 2; ++rr) {
        int r = wave_id * 2 + rr;          // b*512 + i   (scalar)
        int b = r >> 9;

        // row-uniform inputs (scalar loads)
        const float* li = lrf + (size_t)r * 9;
        float li_[9];
#pragma unroll
        for (int t = 0; t < 9; ++t) li_[t] = li[t];
        const float* ci = center + (size_t)r * 6;
        float ci0 = ci[0], ci1 = ci[1], ci2 = ci[2];

        // per-lane static selects from the 9 row-uniform lrf_i values:
        // ori needs A[k] = lrf_i[k][m]; pos needs P[k] = lrf_i[k][c3]
        float A0 = (m == 0) ? li_[0] : (m == 1) ? li_[1] : li_[2];
        float A1 = (m == 0) ? li_[3] : (m == 1) ? li_[4] : li_[5];
        float A2 = (m == 0) ? li_[6] : (m == 1) ? li_[7] : li_[8];
        float P0 = (c3 == 0) ? li_[0] : (c3 == 1) ? li_[1] : li_[2];
        float P1 = (c3 == 0) ? li_[3] : (c3 == 1) ? li_[4] : li_[5];
        float P2 = (c3 == 0) ? li_[6] : (c3 == 1) ? li_[7] : li_[8];

        const float* lb = lrf    + (size_t)b * (G_ * 9);
        const float* cb = center + (size_t)b * (G_ * 6);
        float* orow = out_ori + (size_t)r * (G_ * 9);
        float* prow = out_pos + (size_t)r * (G_ * 3);

        if (lane < 63) {
            // ---- rel_pos row: 24 full iters (21 j each) + tail (8 j) ----
            int offc = jj3 * 6;
#pragma unroll 4
            for (int j0 = 0; j0 < 504; j0 += 21) {
                const float* p = cb + j0 * 6;
                float d0 = p[offc]     - ci0;
                float d1 = p[offc + 1] - ci1;
                float d2 = p[offc + 2] - ci2;
                prow[j0 * 3 + lane] = d0 * P0 + d1 * P1 + d2 * P2;
            }
            if (lane < 24) {                       // j = 504..511
                const float* p = cb + 504 * 6;
                float d0 = p[offc]     - ci0;
                float d1 = p[offc + 1] - ci1;
                float d2 = p[offc + 2] - ci2;
                prow[504 * 3 + lane] = d0 * P0 + d1 * P1 + d2 * P2;
            }

            // ---- rel_ori row: 73 full iters (7 j each) + tail (1 j) ----
            int offo = jj9 * 9 + n;
#pragma unroll 4
            for (int j0 = 0; j0 < 511; j0 += 7) {
                const float* p = lb + j0 * 9;
                float b0 = p[offo];
                float b1 = p[offo + 3];
                float b2 = p[offo + 6];
                orow[j0 * 9 + lane] = A0 * b0 + A1 * b1 + A2 * b2;
            }
            if (lane < 9) {                        // j = 511
                const float* p = lb + 511 * 9;
                float b0 = p[n];
                float b1 = p[n + 3];
                float b2 = p[n + 6];
                orow[511 * 9 + lane] = A0 * b0 + A1 * b1 + A2 * b2;
            }
        }
    }
}

extern "C" void kernel_launch(void* const* d_in, const int* in_sizes, int n_in,
                              void* d_out, int out_size, void* d_ws, size_t ws_size,
                              hipStream_t stream) {
    const float* center = (const float*)d_in[0];
    const float* lrf    = (const float*)d_in[1];
    float* out = (float*)d_out;

    const int B = 32;
    const size_t n_pos = (size_t)B * G_ * G_ * 3;   // 25,165,824 floats
    float* out_pos = out;
    float* out_ori = out + n_pos;

    dim3 grid(2048);    // 8192 waves = 8 blocks/CU * 256 CU, 2 rows/wave
    dim3 block(256);
    hipLaunchKernelGGL(relposori_kernel, grid, block, 0, stream,
                       center, lrf, out_pos, out_ori);
}

// Round 7
// 71.198 us; speedup vs baseline: 2.0194x; 2.0194x over previous
//
#include <hip/hip_runtime.h>

// B=32, G=512
// out layout: [rel_pos (B,G,G,3) | rel_ori (B,G,G,3,3)] flat f32
//
// R2 structure (block LDS staging + syncthreads + aligned float4 writeback)
// at maximum occupancy:
//  - each block owns a HALF row: (b,i, 256 j's) -> LDS 12 KB
//  - 256 thr/block, 1 j per thread; 8 blocks/CU = 32 waves/CU resident
//  - fused writeback: exactly 3 float4 stores/thread, wave-aligned
//    pos/ori split (no intra-wave divergence)

#define G_ 512
#define NB 32

__global__ __launch_bounds__(256, 8) void relposori_kernel(
    const float* __restrict__ center,   // (B,G,6)
    const float* __restrict__ lrf,      // (B,G,3,3)
    float* __restrict__ out_pos,        // (B,G,G,3)
    float* __restrict__ out_ori)        // (B,G,G,3,3)
{
    __shared__ float s[3072];           // 12 KB: [0,768) pos | [768,3072) ori
    float* s_pos = s;
    float* s_ori = s + 768;

    int blk  = blockIdx.x;
    int half = blk & 1;
    int bi   = blk >> 1;                // b*512 + i (uniform)
    int b    = bi >> 9;
    int tid  = threadIdx.x;
    int j    = (half << 8) | tid;

    // uniform (scalar) loads: center_i, lrf_i
    const float* ci = center + (size_t)bi * 6;
    const float* li = lrf    + (size_t)bi * 9;
    float ci0 = ci[0], ci1 = ci[1], ci2 = ci[2];
    float li_[9];
#pragma unroll
    for (int t = 0; t < 9; ++t) li_[t] = li[t];

    // per-thread j inputs (L1/L2-resident)
    size_t bj = (size_t)b * G_ + (size_t)j;
    const float* cj = center + bj * 6;
    const float* lj = lrf    + bj * 9;
    float d0 = cj[0] - ci0, d1 = cj[1] - ci1, d2 = cj[2] - ci2;
    float lj_[9];
#pragma unroll
    for (int t = 0; t < 9; ++t) lj_[t] = lj[t];

    // rel_pos[k] = sum_c d[c] * lrf_i[c][k]
#pragma unroll
    for (int k = 0; k < 3; ++k)
        s_pos[tid * 3 + k] = d0 * li_[k] + d1 * li_[3 + k] + d2 * li_[6 + k];

    // rel_ori[m][n] = sum_k lrf_i[k][m] * lrf_j[k][n]
#pragma unroll
    for (int m = 0; m < 3; ++m)
#pragma unroll
        for (int n = 0; n < 3; ++n)
            s_ori[tid * 9 + m * 3 + n] = li_[m]     * lj_[n]
                                       + li_[3 + m] * lj_[3 + n]
                                       + li_[6 + m] * lj_[6 + n];

    __syncthreads();

    // Fused writeback: 768 float4 total = 3 per thread.
    // t in [0,192): pos (192 f4); t in [192,768): ori (576 f4).
    // Iter 1 splits at t=192 == wave boundary -> no intra-wave divergence.
    const float4* s4  = (const float4*)s;
    float4* op4 = (float4*)out_pos + ((size_t)bi * 384  + (size_t)half * 192);
    float4* oo4 = (float4*)out_ori + ((size_t)bi * 1152 + (size_t)half * 576);

#pragma unroll
    for (int it = 0; it < 3; ++it) {
        int t = tid + (it << 8);
        if (t < 192) op4[t]       = s4[t];
        else         oo4[t - 192] = s4[t];
    }
}

extern "C" void kernel_launch(void* const* d_in, const int* in_sizes, int n_in,
                              void* d_out, int out_size, void* d_ws, size_t ws_size,
                              hipStream_t stream) {
    const float* center = (const float*)d_in[0];
    const float* lrf    = (const float*)d_in[1];
    float* out = (float*)d_out;

    const int B = 32;
    const size_t n_pos = (size_t)B * G_ * G_ * 3;   // 25,165,824 floats
    float* out_pos = out;
    float* out_ori = out + n_pos;

    dim3 grid(B * G_ * 2);   // 32768 half-row blocks
    dim3 block(256);
    hipLaunchKernelGGL(relposori_kernel, grid, block, 0, stream,
                       center, lrf, out_pos, out_ori);
}